// Round 20
// baseline (491.619 us; speedup 1.0000x reference)
//
#include <hip/hip_runtime.h>

#define N_AG 8
#define BTOT 32768
#define OBSF 128
#define ACTF 32
#define HH 4

// ---- workspace byte offsets ----
#define WS_STATS   0u            // 2560 f32
#define WS_SCALES  (16u<<10)     // 4608 f32
#define WS_BIASES  (48u<<10)     // 2048 f32: bias_es[8][256]
#define WS_WQKV    (64u<<10)     // [384][128] bf16 (q|k|v stacked, head-major rows)
#define WS_F2W     (160u<<10)    // [8][32][128] bf16
#define WS_F1W     (224u<<10)    // [8][128][256] bf16
#define WS_WG      (768u<<10)    // [8][256][160] bf16 (BN-folded)
#define WS_IDS     (1536u<<10)   // [8][32768] i32
#define WS_ES      (4u<<20)      // [8][32768][256] bf16 (128 MB, full batch)
#define WS_XI      (136u<<20)    // [8][32768][128] bf16 (64 MB, full batch)
#define WS_QKV     (200u<<20)    // [8][32768][384] bf16 (192 MB: per row q|k|v, col=sec*128+h*32+j)
#define WS_NEED    ((size_t)400<<20)

typedef __attribute__((ext_vector_type(8))) __bf16 bf16x8;
typedef __attribute__((ext_vector_type(8))) short short8;
typedef __attribute__((ext_vector_type(4))) float f32x4;

static __device__ __forceinline__ unsigned short f2bf(float f){
  unsigned u = __builtin_bit_cast(unsigned, f);
  u += 0x7fffu + ((u >> 16) & 1u);
  return (unsigned short)(u >> 16);
}
static __device__ __forceinline__ bf16x8 ldb8(const unsigned short* p){
  return __builtin_bit_cast(bf16x8, *(const short8*)p);
}
// D = A(16x32) * B(32x16) + C ; C/D: col=lane&15, row=(lane>>4)*4+reg
static __device__ __forceinline__ f32x4 mfma16(bf16x8 a, bf16x8 b, f32x4 c){
  return __builtin_amdgcn_mfma_f32_16x16x32_bf16(a, b, c, 0, 0, 0);
}

// ---------------- stats ----------------
__global__ void k_zero(float* stats){
  for (int i = threadIdx.x; i < 2560; i += 256) stats[i] = 0.f;
}

__global__ __launch_bounds__(256) void k_stats_obs(const float* __restrict__ obs,
                                                   float* __restrict__ stats){
  int n = blockIdx.y, ch = blockIdx.x;
  int c = threadIdx.x & 31, r = threadIdx.x >> 5;
  const float4* p = (const float4*)(obs + ((size_t)n*BTOT + (size_t)ch*256 + r)*OBSF) + c;
  float sx=0.f, sy=0.f, sz=0.f, sw=0.f;
  float qx=0.f, qy=0.f, qz=0.f, qw=0.f;
  #pragma unroll 4
  for (int i = 0; i < 32; i++){
    float4 v = p[(size_t)i*8*(OBSF/4)];
    sx += v.x; sy += v.y; sz += v.z; sw += v.w;
    qx += v.x*v.x; qy += v.y*v.y; qz += v.z*v.z; qw += v.w*v.w;
  }
  __shared__ float4 rs[8][32], rq[8][32];
  rs[r][c] = make_float4(sx, sy, sz, sw);
  rq[r][c] = make_float4(qx, qy, qz, qw);
  __syncthreads();
  if (threadIdx.x < 128){
    int f = threadIdx.x;
    float ss = 0.f, qq = 0.f;
    #pragma unroll
    for (int g = 0; g < 8; g++){
      ss += ((const float*)&rs[g][f>>2])[f&3];
      qq += ((const float*)&rq[g][f>>2])[f&3];
    }
    atomicAdd(&stats[n*128 + f], ss);
    atomicAdd(&stats[1024 + n*128 + f], qq);
  }
}

__global__ __launch_bounds__(256) void k_stats_act(const float* __restrict__ act,
                                                   float* __restrict__ stats,
                                                   int* __restrict__ ids){
  int n = blockIdx.y, ch = blockIdx.x;
  int c = threadIdx.x & 7, r = threadIdx.x >> 3;
  int f0 = c*4;
  float sx=0.f, sy=0.f, sz=0.f, sw=0.f;
  float qx=0.f, qy=0.f, qz=0.f, qw=0.f;
  #pragma unroll
  for (int i = 0; i < 4; i++){
    int b = ch*128 + i*32 + r;
    float4 v = *(const float4*)(act + ((size_t)n*BTOT + b)*ACTF + f0);
    sx += v.x; sy += v.y; sz += v.z; sw += v.w;
    qx += v.x*v.x; qy += v.y*v.y; qz += v.z*v.z; qw += v.w*v.w;
    float mv = v.x; int mi = f0;
    if (v.y > mv){ mv = v.y; mi = f0+1; }
    if (v.z > mv){ mv = v.z; mi = f0+2; }
    if (v.w > mv){ mv = v.w; mi = f0+3; }
    #pragma unroll
    for (int m = 1; m <= 4; m <<= 1){
      float ov = __shfl_xor(mv, m);
      int   oi = __shfl_xor(mi, m);
      if (ov > mv || (ov == mv && oi < mi)){ mv = ov; mi = oi; }
    }
    if (c == 0) ids[(size_t)n*BTOT + b] = mi;
  }
  __shared__ float4 rs[32][8], rq[32][8];
  rs[r][c] = make_float4(sx, sy, sz, sw);
  rq[r][c] = make_float4(qx, qy, qz, qw);
  __syncthreads();
  if (threadIdx.x < 32){
    int f = threadIdx.x;
    float ss = 0.f, qq = 0.f;
    #pragma unroll
    for (int g = 0; g < 32; g++){
      ss += ((const float*)&rs[g][f>>2])[f&3];
      qq += ((const float*)&rq[g][f>>2])[f&3];
    }
    atomicAdd(&stats[2048 + n*32 + f], ss);
    atomicAdd(&stats[2304 + n*32 + f], qq);
  }
}

__global__ void k_finalize(const float* __restrict__ stats, const float* __restrict__ gg,
                           const float* __restrict__ gb, const float* __restrict__ sg,
                           const float* __restrict__ sb, float* __restrict__ scales){
  int n = blockIdx.x, f = threadIdx.x;
  if (f < 160){
    float mu, va;
    if (f < 128){ mu = stats[n*128+f] * (1.f/BTOT); va = stats[1024+n*128+f]*(1.f/BTOT) - mu*mu; }
    else { int fa = f-128; mu = stats[2048+n*32+fa]*(1.f/BTOT); va = stats[2304+n*32+fa]*(1.f/BTOT) - mu*mu; }
    float inv = 1.f / sqrtf(va + 1e-5f);
    float a = gg[n*160+f] * inv;
    scales[n*160+f] = a;
    scales[1280 + n*160+f] = gb[n*160+f] - mu*a;
    if (f < 128){
      float a2 = sg[n*128+f] * inv;
      scales[2560 + n*128+f] = a2;
      scales[3584 + n*128+f] = sb[n*128+f] - mu*a2;
    }
  }
}

// ---------------- weight folding / casts ----------------
__global__ void k_fold(const float* __restrict__ g_w, const float* __restrict__ g_b,
                       const float* __restrict__ s_w, const float* __restrict__ s_b,
                       const float* __restrict__ wq, const float* __restrict__ wk,
                       const float* __restrict__ wv, const float* __restrict__ f1w_in,
                       const float* __restrict__ f2w_in, const float* __restrict__ scales,
                       unsigned short* __restrict__ wg, float* __restrict__ bias_es,
                       unsigned short* __restrict__ wqkv, unsigned short* __restrict__ f1w,
                       unsigned short* __restrict__ f2w){
  int blk = blockIdx.x, t = threadIdx.x;
  if (blk < 2048){
    int n = blk >> 8, o = blk & 255;
    float part = 0.f;
    if (t < 160){
      float w, a, c;
      if (o < 128){ w = g_w[((size_t)n*128 + o)*160 + t]; a = scales[n*160+t]; c = scales[1280+n*160+t]; }
      else if (t < 128){ w = s_w[((size_t)n*128 + (o-128))*128 + t]; a = scales[2560+n*128+t]; c = scales[3584+n*128+t]; }
      else { w = 0.f; a = 0.f; c = 0.f; }
      wg[((size_t)n*256 + o)*160 + t] = f2bf(w*a);
      part = w * c;
    }
    __shared__ float red[256];
    red[t] = part; __syncthreads();
    for (int s2 = 128; s2 > 0; s2 >>= 1){ if (t < s2) red[t] += red[t+s2]; __syncthreads(); }
    if (t == 0){
      float base = (o < 128) ? g_b[n*128+o] : s_b[n*128+(o-128)];
      bias_es[n*256+o] = base + red[0];
    }
  } else if (blk < 2240){
    int idx = (blk-2048)*256 + t;                 // 49152: [384][128]
    int r = idx >> 7, f = idx & 127, rr = r & 127;
    const float* src = (r < 128) ? wq : (r < 256 ? wk : wv);
    wqkv[idx] = f2bf(src[rr*128 + f]);
  } else if (blk < 3264){
    int idx = (blk-2240)*256 + t;                 // 262144
    f1w[idx] = f2bf(f1w_in[idx]);
  } else {
    int idx = (blk-3264)*256 + t;                 // 32768
    f2w[idx] = f2bf(f2w_in[idx]);
  }
}

// ---------------- GEMM: e||s = lrelu(X @ Wg'^T + bias') ----------------
// grid (128, 8), 512 threads (round-17/19 config, unchanged).
__global__ __launch_bounds__(512) void k_gemm_es(const float* __restrict__ obs,
    const float* __restrict__ act, const unsigned short* __restrict__ wg,
    const float* __restrict__ biases, unsigned short* __restrict__ es){
  int n = blockIdx.y, mbb = blockIdx.x;
  int tid = threadIdx.x, w = tid >> 6, l = tid & 63, lr = l & 15, lg = l >> 4;
  __shared__ unsigned short wsm[256*160];         // 80KB: agent's folded weights
  {
    const int4* src = (const int4*)(wg + (size_t)n*(256*160));
    int4* dst = (int4*)wsm;
    for (int i = tid; i < 256*160/8; i += 512) dst[i] = src[i];
  }
  int brow = mbb*256 + w*16 + lr;
  size_t bglob = (size_t)n*BTOT + brow;
  float4 x0[10];
  #pragma unroll
  for (int kt = 0; kt < 4; kt++){
    const float4* pa = (const float4*)(obs + bglob*OBSF + kt*32 + lg*8);
    x0[kt*2] = pa[0]; x0[kt*2+1] = pa[1];
  }
  { const float4* pa = (const float4*)(act + bglob*ACTF + lg*8);
    x0[8] = pa[0]; x0[9] = pa[1]; }
  __syncthreads();
  f32x4 zero = {0.f,0.f,0.f,0.f};
  bf16x8 af[5];
  #pragma unroll
  for (int kt = 0; kt < 5; kt++){
    float4 a = x0[kt*2], b = x0[kt*2+1];
    af[kt][0]=(__bf16)a.x; af[kt][1]=(__bf16)a.y; af[kt][2]=(__bf16)a.z; af[kt][3]=(__bf16)a.w;
    af[kt][4]=(__bf16)b.x; af[kt][5]=(__bf16)b.y; af[kt][6]=(__bf16)b.z; af[kt][7]=(__bf16)b.w;
  }
  float4 x1[10];
  #pragma unroll
  for (int kt = 0; kt < 4; kt++){
    const float4* pa = (const float4*)(obs + (bglob+128)*OBSF + kt*32 + lg*8);
    x1[kt*2] = pa[0]; x1[kt*2+1] = pa[1];
  }
  { const float4* pa = (const float4*)(act + (bglob+128)*ACTF + lg*8);
    x1[8] = pa[0]; x1[9] = pa[1]; }
  f32x4 acc[16];
  #pragma unroll
  for (int i = 0; i < 16; i++) acc[i] = zero;
  #pragma unroll
  for (int kt = 0; kt < 5; kt++)
    #pragma unroll
    for (int nt = 0; nt < 16; nt++){
      bf16x8 bf = ldb8(&wsm[(nt*16 + lr)*160 + kt*32 + lg*8]);
      acc[nt] = mfma16(af[kt], bf, acc[nt]);
    }
  #pragma unroll
  for (int nt = 0; nt < 16; nt++){
    int col = nt*16 + lr;
    float bias = biases[n*256 + col];
    #pragma unroll
    for (int r = 0; r < 4; r++){
      float v = acc[nt][r] + bias;
      v = v > 0.f ? v : 0.01f*v;
      int orow = mbb*256 + w*16 + lg*4 + r;
      es[((size_t)n*BTOT + orow)*256 + col] = f2bf(v);
    }
  }
  #pragma unroll
  for (int kt = 0; kt < 5; kt++){
    float4 a = x1[kt*2], b = x1[kt*2+1];
    af[kt][0]=(__bf16)a.x; af[kt][1]=(__bf16)a.y; af[kt][2]=(__bf16)a.z; af[kt][3]=(__bf16)a.w;
    af[kt][4]=(__bf16)b.x; af[kt][5]=(__bf16)b.y; af[kt][6]=(__bf16)b.z; af[kt][7]=(__bf16)b.w;
  }
  #pragma unroll
  for (int i = 0; i < 16; i++) acc[i] = zero;
  #pragma unroll
  for (int kt = 0; kt < 5; kt++)
    #pragma unroll
    for (int nt = 0; nt < 16; nt++){
      bf16x8 bf = ldb8(&wsm[(nt*16 + lr)*160 + kt*32 + lg*8]);
      acc[nt] = mfma16(af[kt], bf, acc[nt]);
    }
  #pragma unroll
  for (int nt = 0; nt < 16; nt++){
    int col = nt*16 + lr;
    float bias = biases[n*256 + col];
    #pragma unroll
    for (int r = 0; r < 4; r++){
      float v = acc[nt][r] + bias;
      v = v > 0.f ? v : 0.01f*v;
      int orow = mbb*256 + 128 + w*16 + lg*4 + r;
      es[((size_t)n*BTOT + orow)*256 + col] = f2bf(v);
    }
  }
}

// ---------------- qkv projection GEMM (attn part 1) ----------------
// grid (128, 8), 512 threads: qkvg[n][row][384] = es[n][row][0:128] @ wqkv^T,
// col = sec*128 + h*32 + j (same as wqkv row index). lrelu on v (col>=256).
// Weight staging padded to stride 132 (f1T's proven conflict-free layout).
// Pure GEMM: no inner barriers, same MFMA order/f2bf as the fused kernel.
__global__ __launch_bounds__(512) void k_qkv(const unsigned short* __restrict__ es,
    const unsigned short* __restrict__ wqkv, unsigned short* __restrict__ qkvg){
  int n = blockIdx.y, mbb = blockIdx.x;
  int tid = threadIdx.x, w = tid >> 6, l = tid & 63, lr = l & 15, lg = l >> 4;
  __shared__ unsigned short wsm[384*132];         // 99KB padded
  for (int i = tid; i < 384*16; i += 512){
    int r = i >> 4, c = (i & 15)*8;
    *(int4*)&wsm[r*132 + c] = *(const int4*)&wqkv[(size_t)r*128 + c];
  }
  __syncthreads();
  f32x4 zero = {0.f,0.f,0.f,0.f};
  #pragma unroll
  for (int sub = 0; sub < 2; sub++){
    int row = mbb*256 + sub*128 + w*16 + lr;
    bf16x8 af[4];
    #pragma unroll
    for (int kt = 0; kt < 4; kt++)
      af[kt] = ldb8(&es[((size_t)n*BTOT + row)*256 + kt*32 + lg*8]);
    f32x4 acc[24];
    #pragma unroll
    for (int i = 0; i < 24; i++) acc[i] = zero;
    #pragma unroll
    for (int kt = 0; kt < 4; kt++)
      #pragma unroll
      for (int nt = 0; nt < 24; nt++){
        bf16x8 bf = ldb8(&wsm[(nt*16 + lr)*132 + kt*32 + lg*8]);
        acc[nt] = mfma16(af[kt], bf, acc[nt]);
      }
    #pragma unroll
    for (int nt = 0; nt < 24; nt++){
      int col = nt*16 + lr;
      #pragma unroll
      for (int r = 0; r < 4; r++){
        float v = acc[nt][r];
        if (nt >= 16) v = v > 0.f ? v : 0.01f*v;   // lrelu on v section only
        int orow = mbb*256 + sub*128 + w*16 + lg*4 + r;
        qkvg[((size_t)n*BTOT + orow)*384 + col] = f2bf(v);
      }
    }
  }
}

// ---------------- attention scalar (attn part 2) ----------------
// grid 2048, 256 threads, thread=(nq,bi,dh) exactly as the fused kernel's scalar
// phase, reading q/K/V from global qkvg. NO barriers, NO LDS, high occupancy.
// Per block: 16 b-rows x 8 agents x 768B = 96KB working set, K/V rows reused
// by all 8 nq via L1/L2. Arithmetic order identical to the fused kernel.
__global__ __launch_bounds__(256) void k_attnsc(const unsigned short* __restrict__ qkvg,
    unsigned short* __restrict__ xi){
  int bt = blockIdx.x;
  int tid = threadIdx.x;
  int dh = tid & 1, bi = (tid >> 1) & 15, nq = tid >> 5;
  int b = bt*16 + bi;
  #pragma unroll
  for (int h = 0; h < HH; h++){
    float qv[16];
    { const unsigned short* qp = &qkvg[((size_t)nq*BTOT + b)*384 + h*32 + dh*16];
      bf16x8 t0 = ldb8(qp);
      bf16x8 t1 = ldb8(qp + 8);
      #pragma unroll
      for (int i = 0; i < 8; i++){ qv[i] = (float)t0[i]; qv[8+i] = (float)t1[i]; } }
    float lgt[8];
    #pragma unroll
    for (int m = 0; m < 8; m++){
      const unsigned short* kp = &qkvg[((size_t)m*BTOT + b)*384 + 128 + h*32 + dh*16];
      bf16x8 k0 = ldb8(kp);
      bf16x8 k1 = ldb8(kp + 8);
      float d = 0.f;
      #pragma unroll
      for (int i = 0; i < 8; i++){ d += qv[i]*(float)k0[i]; d += qv[8+i]*(float)k1[i]; }
      d += __shfl_xor(d, 1);
      lgt[m] = d * 0.17677669529663687f;          // 1/sqrt(32)
    }
    float mx = -1e30f;
    #pragma unroll
    for (int m = 0; m < 8; m++) if (m != nq) mx = fmaxf(mx, lgt[m]);
    float p[8], sum = 0.f;
    #pragma unroll
    for (int m = 0; m < 8; m++){ p[m] = (m == nq) ? 0.f : __expf(lgt[m] - mx); sum += p[m]; }
    float inv = 1.f / sum;
    float xa[16];
    #pragma unroll
    for (int i = 0; i < 16; i++) xa[i] = 0.f;
    #pragma unroll
    for (int m = 0; m < 8; m++){
      float al = p[m]*inv;
      const unsigned short* vp = &qkvg[((size_t)m*BTOT + b)*384 + 256 + h*32 + dh*16];
      bf16x8 v0 = ldb8(vp);
      bf16x8 v1 = ldb8(vp + 8);
      #pragma unroll
      for (int i = 0; i < 8; i++){ xa[i] += al*(float)v0[i]; xa[8+i] += al*(float)v1[i]; }
    }
    short8 o0, o1;
    #pragma unroll
    for (int i = 0; i < 8; i++){ o0[i] = (short)f2bf(xa[i]); o1[i] = (short)f2bf(xa[8+i]); }
    size_t orow = (size_t)nq*BTOT + b;
    *(short8*)&xi[orow*128 + h*32 + dh*16]     = o0;
    *(short8*)&xi[orow*128 + h*32 + dh*16 + 8] = o1;
  }
}

// ---------------- f1 -> f2 -> gather ----------------
// grid (128, 8), 512 threads (round-16 winner, unchanged).
__global__ __launch_bounds__(512) void k_gemm_f(const unsigned short* __restrict__ xi,
    const unsigned short* __restrict__ es, const unsigned short* __restrict__ f1w,
    const float* __restrict__ f1b, const unsigned short* __restrict__ f2w,
    const float* __restrict__ f2b, const int* __restrict__ ids,
    float* __restrict__ out){
  int n = blockIdx.y, mbb = blockIdx.x;
  int tid = threadIdx.x, w = tid >> 6, l = tid & 63, lr = l & 15, lg = l >> 4;
  __shared__ unsigned short f1T[128*264];          // 67.6KB
  __shared__ unsigned short f2T[32*136];           // 8.7KB
  __shared__ unsigned short h1T[128*136];          // 34.8KB
  __shared__ float allq[128*32];                   // 16KB
  for (int i = tid; i < 128*32; i += 512){
    int r = i >> 5, c = (i & 31)*8;
    *(int4*)&f1T[r*264 + c] = *(const int4*)&f1w[((size_t)n*128 + r)*256 + c];
  }
  for (int i = tid; i < 32*16; i += 512){
    int r = i >> 4, c = (i & 15)*8;
    *(int4*)&f2T[r*136 + c] = *(const int4*)&f2w[((size_t)n*32 + r)*128 + c];
  }
  bf16x8 xf[2][8];
  {
    int arow0 = mbb*256 + w*16 + lr;
    #pragma unroll
    for (int kt = 0; kt < 4; kt++)
      xf[0][kt] = ldb8(&xi[((size_t)n*BTOT + arow0)*128 + kt*32 + lg*8]);
    #pragma unroll
    for (int kt = 0; kt < 4; kt++)
      xf[0][4+kt] = ldb8(&es[((size_t)n*BTOT + arow0)*256 + 128 + kt*32 + lg*8]);
  }
  __syncthreads();
  f32x4 zero = {0.f,0.f,0.f,0.f};
  #pragma unroll
  for (int sub = 0; sub < 2; sub++){
    const int cur = sub & 1, nxt = cur ^ 1;
    int mb = mbb*2 + sub;
    int arow = mb*128 + w*16 + lr;
    if (sub < 1){
      int arown = arow + 128;
      #pragma unroll
      for (int kt = 0; kt < 4; kt++)
        xf[nxt][kt] = ldb8(&xi[((size_t)n*BTOT + arown)*128 + kt*32 + lg*8]);
      #pragma unroll
      for (int kt = 0; kt < 4; kt++)
        xf[nxt][4+kt] = ldb8(&es[((size_t)n*BTOT + arown)*256 + 128 + kt*32 + lg*8]);
    }
    f32x4 a1[8];
    #pragma unroll
    for (int i = 0; i < 8; i++) a1[i] = zero;
    #pragma unroll
    for (int kt = 0; kt < 8; kt++)
      #pragma unroll
      for (int nt = 0; nt < 8; nt++){
        bf16x8 bf = ldb8(&f1T[(nt*16 + lr)*264 + kt*32 + lg*8]);
        a1[nt] = mfma16(xf[cur][kt], bf, a1[nt]);
      }
    #pragma unroll
    for (int nt = 0; nt < 8; nt++){
      int col = nt*16 + lr;
      float bias = f1b[n*128 + col];
      #pragma unroll
      for (int r = 0; r < 4; r++){
        float v = a1[nt][r] + bias;
        v = v > 0.f ? v : 0.01f*v;
        h1T[(w*16 + lg*4 + r)*136 + col] = f2bf(v);
      }
    }
    __syncthreads();
    f32x4 a2[2];
    a2[0] = zero; a2[1] = zero;
    #pragma unroll
    for (int kt = 0; kt < 4; kt++){
      int f0 = kt*32 + lg*8;
      bf16x8 hf = ldb8(&h1T[(w*16 + lr)*136 + f0]);
      #pragma unroll
      for (int nt = 0; nt < 2; nt++){
        bf16x8 bf = ldb8(&f2T[(nt*16 + lr)*136 + f0]);
        a2[nt] = mfma16(hf, bf, a2[nt]);
      }
    }
    #pragma unroll
    for (int nt = 0; nt < 2; nt++){
      int col = nt*16 + lr;
      float bias = f2b[n*32 + col];
      #pragma unroll
      for (int r = 0; r < 4; r++)
        allq[(w*16 + lg*4 + r)*32 + col] = a2[nt][r] + bias;
    }
    __syncthreads();
    if (tid < 128){
      size_t bglob = (size_t)mb*128 + tid;
      int id = ids[(size_t)n*BTOT + bglob];
      out[(size_t)n*BTOT + bglob] = allq[tid*32 + id];
    }
  }
}

extern "C" void kernel_launch(void* const* d_in, const int* in_sizes, int n_in,
                              void* d_out, int out_size, void* d_ws, size_t ws_size,
                              hipStream_t stream){
  if (ws_size < WS_NEED) return;
  const float* obs  = (const float*)d_in[0];
  const float* act  = (const float*)d_in[1];
  const float* gg   = (const float*)d_in[2];
  const float* gb   = (const float*)d_in[3];
  const float* sg   = (const float*)d_in[4];
  const float* sb   = (const float*)d_in[5];
  const float* g_w  = (const float*)d_in[6];
  const float* g_b  = (const float*)d_in[7];
  const float* s_w  = (const float*)d_in[8];
  const float* s_b  = (const float*)d_in[9];
  const float* wq   = (const float*)d_in[10];
  const float* wk   = (const float*)d_in[11];
  const float* wv   = (const float*)d_in[12];
  const float* f1w_in = (const float*)d_in[13];
  const float* f1b  = (const float*)d_in[14];
  const float* f2w_in = (const float*)d_in[15];
  const float* f2b  = (const float*)d_in[16];
  char* ws = (char*)d_ws;
  float* stats   = (float*)(ws + WS_STATS);
  float* scales  = (float*)(ws + WS_SCALES);
  float* bias_es = (float*)(ws + WS_BIASES);
  unsigned short* wqkv = (unsigned short*)(ws + WS_WQKV);
  unsigned short* f2wb = (unsigned short*)(ws + WS_F2W);
  unsigned short* f1wb = (unsigned short*)(ws + WS_F1W);
  unsigned short* wg   = (unsigned short*)(ws + WS_WG);
  int* ids             = (int*)(ws + WS_IDS);
  unsigned short* esb  = (unsigned short*)(ws + WS_ES);
  unsigned short* xib  = (unsigned short*)(ws + WS_XI);
  unsigned short* qkvg = (unsigned short*)(ws + WS_QKV);
  float* out = (float*)d_out;

  k_zero<<<1, 256, 0, stream>>>(stats);
  k_stats_obs<<<dim3(128,8), 256, 0, stream>>>(obs, stats);
  k_stats_act<<<dim3(256,8), 256, 0, stream>>>(act, stats, ids);
  k_finalize<<<8, 256, 0, stream>>>(stats, gg, gb, sg, sb, scales);
  k_fold<<<3392, 256, 0, stream>>>(g_w, g_b, s_w, s_b, wq, wk, wv, f1w_in, f2w_in,
                                   scales, wg, bias_es, wqkv, f1wb, f2wb);
  k_gemm_es<<<dim3(128,8), 512, 0, stream>>>(obs, act, wg, bias_es, esb);
  k_qkv<<<dim3(128,8), 512, 0, stream>>>(esb, wqkv, qkvg);
  k_attnsc<<<2048, 256, 0, stream>>>(qkvg, xib);
  k_gemm_f<<<dim3(128,8), 512, 0, stream>>>(xib, esb, f1wb, f1b, f2wb, f2b, ids, out);
}

// Round 21
// 299.105 us; speedup vs baseline: 1.6436x; 1.6436x over previous
//
#include <hip/hip_runtime.h>

#define N_AG 8
#define BTOT 32768
#define OBSF 128
#define ACTF 32
#define HH 4

// ---- workspace byte offsets ----
#define WS_STATS   0u            // 2560 f32
#define WS_SCALES  (16u<<10)     // 4608 f32
#define WS_BIASES  (48u<<10)     // 2048 f32: bias_es[8][256]
#define WS_WQKV    (64u<<10)     // [384][128] bf16 (q|k|v stacked, head-major rows)
#define WS_F2W     (160u<<10)    // [8][32][128] bf16
#define WS_F1W     (224u<<10)    // [8][128][256] bf16
#define WS_WG      (768u<<10)    // [8][256][160] bf16 (BN-folded)
#define WS_IDS     (1536u<<10)   // [8][32768] i32
#define WS_ES      (4u<<20)      // [8][32768][256] bf16 (128 MB, full batch)
#define WS_XI      (136u<<20)    // [8][32768][128] bf16 (64 MB, full batch)
#define WS_NEED    ((size_t)200<<20)

typedef __attribute__((ext_vector_type(8))) __bf16 bf16x8;
typedef __attribute__((ext_vector_type(8))) short short8;
typedef __attribute__((ext_vector_type(4))) float f32x4;

static __device__ __forceinline__ unsigned short f2bf(float f){
  unsigned u = __builtin_bit_cast(unsigned, f);
  u += 0x7fffu + ((u >> 16) & 1u);
  return (unsigned short)(u >> 16);
}
static __device__ __forceinline__ bf16x8 ldb8(const unsigned short* p){
  return __builtin_bit_cast(bf16x8, *(const short8*)p);
}
// D = A(16x32) * B(32x16) + C ; C/D: col=lane&15, row=(lane>>4)*4+reg
static __device__ __forceinline__ f32x4 mfma16(bf16x8 a, bf16x8 b, f32x4 c){
  return __builtin_amdgcn_mfma_f32_16x16x32_bf16(a, b, c, 0, 0, 0);
}

// ---------------- stats ----------------
__global__ void k_zero(float* stats){
  for (int i = threadIdx.x; i < 2560; i += 256) stats[i] = 0.f;
}

__global__ __launch_bounds__(256) void k_stats_obs(const float* __restrict__ obs,
                                                   float* __restrict__ stats){
  int n = blockIdx.y, ch = blockIdx.x;
  int c = threadIdx.x & 31, r = threadIdx.x >> 5;
  const float4* p = (const float4*)(obs + ((size_t)n*BTOT + (size_t)ch*256 + r)*OBSF) + c;
  float sx=0.f, sy=0.f, sz=0.f, sw=0.f;
  float qx=0.f, qy=0.f, qz=0.f, qw=0.f;
  #pragma unroll 4
  for (int i = 0; i < 32; i++){
    float4 v = p[(size_t)i*8*(OBSF/4)];
    sx += v.x; sy += v.y; sz += v.z; sw += v.w;
    qx += v.x*v.x; qy += v.y*v.y; qz += v.z*v.z; qw += v.w*v.w;
  }
  __shared__ float4 rs[8][32], rq[8][32];
  rs[r][c] = make_float4(sx, sy, sz, sw);
  rq[r][c] = make_float4(qx, qy, qz, qw);
  __syncthreads();
  if (threadIdx.x < 128){
    int f = threadIdx.x;
    float ss = 0.f, qq = 0.f;
    #pragma unroll
    for (int g = 0; g < 8; g++){
      ss += ((const float*)&rs[g][f>>2])[f&3];
      qq += ((const float*)&rq[g][f>>2])[f&3];
    }
    atomicAdd(&stats[n*128 + f], ss);
    atomicAdd(&stats[1024 + n*128 + f], qq);
  }
}

__global__ __launch_bounds__(256) void k_stats_act(const float* __restrict__ act,
                                                   float* __restrict__ stats,
                                                   int* __restrict__ ids){
  int n = blockIdx.y, ch = blockIdx.x;
  int c = threadIdx.x & 7, r = threadIdx.x >> 3;
  int f0 = c*4;
  float sx=0.f, sy=0.f, sz=0.f, sw=0.f;
  float qx=0.f, qy=0.f, qz=0.f, qw=0.f;
  #pragma unroll
  for (int i = 0; i < 4; i++){
    int b = ch*128 + i*32 + r;
    float4 v = *(const float4*)(act + ((size_t)n*BTOT + b)*ACTF + f0);
    sx += v.x; sy += v.y; sz += v.z; sw += v.w;
    qx += v.x*v.x; qy += v.y*v.y; qz += v.z*v.z; qw += v.w*v.w;
    float mv = v.x; int mi = f0;
    if (v.y > mv){ mv = v.y; mi = f0+1; }
    if (v.z > mv){ mv = v.z; mi = f0+2; }
    if (v.w > mv){ mv = v.w; mi = f0+3; }
    #pragma unroll
    for (int m = 1; m <= 4; m <<= 1){
      float ov = __shfl_xor(mv, m);
      int   oi = __shfl_xor(mi, m);
      if (ov > mv || (ov == mv && oi < mi)){ mv = ov; mi = oi; }
    }
    if (c == 0) ids[(size_t)n*BTOT + b] = mi;
  }
  __shared__ float4 rs[32][8], rq[32][8];
  rs[r][c] = make_float4(sx, sy, sz, sw);
  rq[r][c] = make_float4(qx, qy, qz, qw);
  __syncthreads();
  if (threadIdx.x < 32){
    int f = threadIdx.x;
    float ss = 0.f, qq = 0.f;
    #pragma unroll
    for (int g = 0; g < 32; g++){
      ss += ((const float*)&rs[g][f>>2])[f&3];
      qq += ((const float*)&rq[g][f>>2])[f&3];
    }
    atomicAdd(&stats[2048 + n*32 + f], ss);
    atomicAdd(&stats[2304 + n*32 + f], qq);
  }
}

__global__ void k_finalize(const float* __restrict__ stats, const float* __restrict__ gg,
                           const float* __restrict__ gb, const float* __restrict__ sg,
                           const float* __restrict__ sb, float* __restrict__ scales){
  int n = blockIdx.x, f = threadIdx.x;
  if (f < 160){
    float mu, va;
    if (f < 128){ mu = stats[n*128+f] * (1.f/BTOT); va = stats[1024+n*128+f]*(1.f/BTOT) - mu*mu; }
    else { int fa = f-128; mu = stats[2048+n*32+fa]*(1.f/BTOT); va = stats[2304+n*32+fa]*(1.f/BTOT) - mu*mu; }
    float inv = 1.f / sqrtf(va + 1e-5f);
    float a = gg[n*160+f] * inv;
    scales[n*160+f] = a;
    scales[1280 + n*160+f] = gb[n*160+f] - mu*a;
    if (f < 128){
      float a2 = sg[n*128+f] * inv;
      scales[2560 + n*128+f] = a2;
      scales[3584 + n*128+f] = sb[n*128+f] - mu*a2;
    }
  }
}

// ---------------- weight folding / casts ----------------
__global__ void k_fold(const float* __restrict__ g_w, const float* __restrict__ g_b,
                       const float* __restrict__ s_w, const float* __restrict__ s_b,
                       const float* __restrict__ wq, const float* __restrict__ wk,
                       const float* __restrict__ wv, const float* __restrict__ f1w_in,
                       const float* __restrict__ f2w_in, const float* __restrict__ scales,
                       unsigned short* __restrict__ wg, float* __restrict__ bias_es,
                       unsigned short* __restrict__ wqkv, unsigned short* __restrict__ f1w,
                       unsigned short* __restrict__ f2w){
  int blk = blockIdx.x, t = threadIdx.x;
  if (blk < 2048){
    int n = blk >> 8, o = blk & 255;
    float part = 0.f;
    if (t < 160){
      float w, a, c;
      if (o < 128){ w = g_w[((size_t)n*128 + o)*160 + t]; a = scales[n*160+t]; c = scales[1280+n*160+t]; }
      else if (t < 128){ w = s_w[((size_t)n*128 + (o-128))*128 + t]; a = scales[2560+n*128+t]; c = scales[3584+n*128+t]; }
      else { w = 0.f; a = 0.f; c = 0.f; }
      wg[((size_t)n*256 + o)*160 + t] = f2bf(w*a);
      part = w * c;
    }
    __shared__ float red[256];
    red[t] = part; __syncthreads();
    for (int s2 = 128; s2 > 0; s2 >>= 1){ if (t < s2) red[t] += red[t+s2]; __syncthreads(); }
    if (t == 0){
      float base = (o < 128) ? g_b[n*128+o] : s_b[n*128+(o-128)];
      bias_es[n*256+o] = base + red[0];
    }
  } else if (blk < 2240){
    int idx = (blk-2048)*256 + t;                 // 49152: [384][128]
    int r = idx >> 7, f = idx & 127, rr = r & 127;
    const float* src = (r < 128) ? wq : (r < 256 ? wk : wv);
    wqkv[idx] = f2bf(src[rr*128 + f]);
  } else if (blk < 3264){
    int idx = (blk-2240)*256 + t;                 // 262144
    f1w[idx] = f2bf(f1w_in[idx]);
  } else {
    int idx = (blk-3264)*256 + t;                 // 32768
    f2w[idx] = f2bf(f2w_in[idx]);
  }
}

// ---------------- GEMM: e||s = lrelu(X @ Wg'^T + bias') ----------------
// grid (128, 8), 512 threads: 80KB wsm staged once per 256 rows,
// 2 M-subtiles of 128 rows, A-loads software-pipelined (round-17).
__global__ __launch_bounds__(512) void k_gemm_es(const float* __restrict__ obs,
    const float* __restrict__ act, const unsigned short* __restrict__ wg,
    const float* __restrict__ biases, unsigned short* __restrict__ es){
  int n = blockIdx.y, mbb = blockIdx.x;
  int tid = threadIdx.x, w = tid >> 6, l = tid & 63, lr = l & 15, lg = l >> 4;
  __shared__ unsigned short wsm[256*160];         // 80KB: agent's folded weights
  {
    const int4* src = (const int4*)(wg + (size_t)n*(256*160));
    int4* dst = (int4*)wsm;
    for (int i = tid; i < 256*160/8; i += 512) dst[i] = src[i];
  }
  int brow = mbb*256 + w*16 + lr;
  size_t bglob = (size_t)n*BTOT + brow;
  float4 x0[10];
  #pragma unroll
  for (int kt = 0; kt < 4; kt++){
    const float4* pa = (const float4*)(obs + bglob*OBSF + kt*32 + lg*8);
    x0[kt*2] = pa[0]; x0[kt*2+1] = pa[1];
  }
  { const float4* pa = (const float4*)(act + bglob*ACTF + lg*8);
    x0[8] = pa[0]; x0[9] = pa[1]; }
  __syncthreads();
  f32x4 zero = {0.f,0.f,0.f,0.f};
  bf16x8 af[5];
  #pragma unroll
  for (int kt = 0; kt < 5; kt++){
    float4 a = x0[kt*2], b = x0[kt*2+1];
    af[kt][0]=(__bf16)a.x; af[kt][1]=(__bf16)a.y; af[kt][2]=(__bf16)a.z; af[kt][3]=(__bf16)a.w;
    af[kt][4]=(__bf16)b.x; af[kt][5]=(__bf16)b.y; af[kt][6]=(__bf16)b.z; af[kt][7]=(__bf16)b.w;
  }
  float4 x1[10];
  #pragma unroll
  for (int kt = 0; kt < 4; kt++){
    const float4* pa = (const float4*)(obs + (bglob+128)*OBSF + kt*32 + lg*8);
    x1[kt*2] = pa[0]; x1[kt*2+1] = pa[1];
  }
  { const float4* pa = (const float4*)(act + (bglob+128)*ACTF + lg*8);
    x1[8] = pa[0]; x1[9] = pa[1]; }
  f32x4 acc[16];
  #pragma unroll
  for (int i = 0; i < 16; i++) acc[i] = zero;
  #pragma unroll
  for (int kt = 0; kt < 5; kt++)
    #pragma unroll
    for (int nt = 0; nt < 16; nt++){
      bf16x8 bf = ldb8(&wsm[(nt*16 + lr)*160 + kt*32 + lg*8]);
      acc[nt] = mfma16(af[kt], bf, acc[nt]);
    }
  #pragma unroll
  for (int nt = 0; nt < 16; nt++){
    int col = nt*16 + lr;
    float bias = biases[n*256 + col];
    #pragma unroll
    for (int r = 0; r < 4; r++){
      float v = acc[nt][r] + bias;
      v = v > 0.f ? v : 0.01f*v;
      int orow = mbb*256 + w*16 + lg*4 + r;
      es[((size_t)n*BTOT + orow)*256 + col] = f2bf(v);
    }
  }
  #pragma unroll
  for (int kt = 0; kt < 5; kt++){
    float4 a = x1[kt*2], b = x1[kt*2+1];
    af[kt][0]=(__bf16)a.x; af[kt][1]=(__bf16)a.y; af[kt][2]=(__bf16)a.z; af[kt][3]=(__bf16)a.w;
    af[kt][4]=(__bf16)b.x; af[kt][5]=(__bf16)b.y; af[kt][6]=(__bf16)b.z; af[kt][7]=(__bf16)b.w;
  }
  #pragma unroll
  for (int i = 0; i < 16; i++) acc[i] = zero;
  #pragma unroll
  for (int kt = 0; kt < 5; kt++)
    #pragma unroll
    for (int nt = 0; nt < 16; nt++){
      bf16x8 bf = ldb8(&wsm[(nt*16 + lr)*160 + kt*32 + lg*8]);
      acc[nt] = mfma16(af[kt], bf, acc[nt]);
    }
  #pragma unroll
  for (int nt = 0; nt < 16; nt++){
    int col = nt*16 + lr;
    float bias = biases[n*256 + col];
    #pragma unroll
    for (int r = 0; r < 4; r++){
      float v = acc[nt][r] + bias;
      v = v > 0.f ? v : 0.01f*v;
      int orow = mbb*256 + 128 + w*16 + lg*4 + r;
      es[((size_t)n*BTOT + orow)*256 + col] = f2bf(v);
    }
  }
}

// ---------------- attention: qkv MFMA + leave-one-out softmax + xi ----------------
// Round-9 byte-exact winner (256 threads, grid 2048): single 26.6KB bf16 qkvT,
// 2 barriers/head, no wave clamp, no setprio, 116 VGPR for deep load pipelining.
// All variants (setprio r10, head-split r12, packed-writes r13, f32-LDS r14,
// wide-blocks r18, kernel-split r20) regressed or tied; this is the record.
__global__ __launch_bounds__(256) void k_attn(const unsigned short* __restrict__ es,
    const unsigned short* __restrict__ wqkv, unsigned short* __restrict__ xi){
  int bt = blockIdx.x;
  int tid = threadIdx.x, w = tid >> 6, l = tid & 63, lr = l & 15, lg = l >> 4;
  __shared__ unsigned short qkvT[128][104];       // q:0..32 k:32..64 v:64..96 (26.6KB)
  bf16x8 e0[4], e1[4];
  {
    int r0 = w*32 + lr, r1 = r0 + 16;
    const unsigned short* p0 = &es[((size_t)(r0>>4)*BTOT + bt*16 + (r0&15))*256];
    const unsigned short* p1 = &es[((size_t)(r1>>4)*BTOT + bt*16 + (r1&15))*256];
    #pragma unroll
    for (int kt = 0; kt < 4; kt++){
      e0[kt] = ldb8(p0 + kt*32 + lg*8);
      e1[kt] = ldb8(p1 + kt*32 + lg*8);
    }
  }
  #pragma unroll
  for (int h = 0; h < HH; h++){
    f32x4 zero = {0.f,0.f,0.f,0.f};
    f32x4 acc[2][6];
    #pragma unroll
    for (int mt = 0; mt < 2; mt++)
      #pragma unroll
      for (int nt = 0; nt < 6; nt++) acc[mt][nt] = zero;
    #pragma unroll
    for (int kt = 0; kt < 4; kt++){
      int f0 = kt*32 + lg*8;
      #pragma unroll
      for (int nt = 0; nt < 6; nt++){
        int r = nt*16 + lr, sec = r >> 5, j = r & 31;   // q/k/v section
        bf16x8 bf = ldb8(&wqkv[((size_t)sec*128 + h*32 + j)*128 + f0]);
        acc[0][nt] = mfma16(e0[kt], bf, acc[0][nt]);
        acc[1][nt] = mfma16(e1[kt], bf, acc[1][nt]);
      }
    }
    __syncthreads();                               // barrier A: scalar readers of h-1 done
    #pragma unroll
    for (int mt = 0; mt < 2; mt++)
      #pragma unroll
      for (int nt = 0; nt < 6; nt++)
        #pragma unroll
        for (int r = 0; r < 4; r++){
          float v = acc[mt][nt][r];
          if (nt >= 4) v = v > 0.f ? v : 0.01f*v;   // lrelu on v only
          qkvT[w*32 + mt*16 + lg*4 + r][nt*16 + lr] = f2bf(v);
        }
    __syncthreads();                               // barrier B: qkvT[h] visible
    { // attention: thread = (nq, bi, d-half)
      int dh = tid & 1, bi = (tid >> 1) & 15, nq = tid >> 5;
      int rq = nq*16 + bi;
      float qv[16];
      { bf16x8 t0 = ldb8(&qkvT[rq][dh*16]);
        bf16x8 t1 = ldb8(&qkvT[rq][dh*16 + 8]);
        #pragma unroll
        for (int i = 0; i < 8; i++){ qv[i] = (float)t0[i]; qv[8+i] = (float)t1[i]; } }
      float lgt[8];
      #pragma unroll
      for (int m = 0; m < 8; m++){
        bf16x8 k0 = ldb8(&qkvT[m*16+bi][32 + dh*16]);
        bf16x8 k1 = ldb8(&qkvT[m*16+bi][32 + dh*16 + 8]);
        float d = 0.f;
        #pragma unroll
        for (int i = 0; i < 8; i++){ d += qv[i]*(float)k0[i]; d += qv[8+i]*(float)k1[i]; }
        d += __shfl_xor(d, 1);
        lgt[m] = d * 0.17677669529663687f;        // 1/sqrt(32)
      }
      float mx = -1e30f;
      #pragma unroll
      for (int m = 0; m < 8; m++) if (m != nq) mx = fmaxf(mx, lgt[m]);
      float p[8], sum = 0.f;
      #pragma unroll
      for (int m = 0; m < 8; m++){ p[m] = (m == nq) ? 0.f : __expf(lgt[m] - mx); sum += p[m]; }
      float inv = 1.f / sum;
      float xa[16];
      #pragma unroll
      for (int i = 0; i < 16; i++) xa[i] = 0.f;
      #pragma unroll
      for (int m = 0; m < 8; m++){
        float al = p[m]*inv;
        bf16x8 v0 = ldb8(&qkvT[m*16+bi][64 + dh*16]);
        bf16x8 v1 = ldb8(&qkvT[m*16+bi][64 + dh*16 + 8]);
        #pragma unroll
        for (int i = 0; i < 8; i++){ xa[i] += al*(float)v0[i]; xa[8+i] += al*(float)v1[i]; }
      }
      short8 o0, o1;
      #pragma unroll
      for (int i = 0; i < 8; i++){ o0[i] = (short)f2bf(xa[i]); o1[i] = (short)f2bf(xa[8+i]); }
      size_t orow = (size_t)nq*BTOT + bt*16 + bi;
      *(short8*)&xi[orow*128 + h*32 + dh*16]     = o0;
      *(short8*)&xi[orow*128 + h*32 + dh*16 + 8] = o1;
    }
  }
}

// ---------------- f1 -> f2 -> gather ----------------
// grid (128, 8), 512 threads (round-16 winner, unchanged).
__global__ __launch_bounds__(512) void k_gemm_f(const unsigned short* __restrict__ xi,
    const unsigned short* __restrict__ es, const unsigned short* __restrict__ f1w,
    const float* __restrict__ f1b, const unsigned short* __restrict__ f2w,
    const float* __restrict__ f2b, const int* __restrict__ ids,
    float* __restrict__ out){
  int n = blockIdx.y, mbb = blockIdx.x;
  int tid = threadIdx.x, w = tid >> 6, l = tid & 63, lr = l & 15, lg = l >> 4;
  __shared__ unsigned short f1T[128*264];          // 67.6KB
  __shared__ unsigned short f2T[32*136];           // 8.7KB
  __shared__ unsigned short h1T[128*136];          // 34.8KB
  __shared__ float allq[128*32];                   // 16KB
  for (int i = tid; i < 128*32; i += 512){
    int r = i >> 5, c = (i & 31)*8;
    *(int4*)&f1T[r*264 + c] = *(const int4*)&f1w[((size_t)n*128 + r)*256 + c];
  }
  for (int i = tid; i < 32*16; i += 512){
    int r = i >> 4, c = (i & 15)*8;
    *(int4*)&f2T[r*136 + c] = *(const int4*)&f2w[((size_t)n*32 + r)*128 + c];
  }
  bf16x8 xf[2][8];
  {
    int arow0 = mbb*256 + w*16 + lr;
    #pragma unroll
    for (int kt = 0; kt < 4; kt++)
      xf[0][kt] = ldb8(&xi[((size_t)n*BTOT + arow0)*128 + kt*32 + lg*8]);
    #pragma unroll
    for (int kt = 0; kt < 4; kt++)
      xf[0][4+kt] = ldb8(&es[((size_t)n*BTOT + arow0)*256 + 128 + kt*32 + lg*8]);
  }
  __syncthreads();
  f32x4 zero = {0.f,0.f,0.f,0.f};
  #pragma unroll
  for (int sub = 0; sub < 2; sub++){
    const int cur = sub & 1, nxt = cur ^ 1;
    int mb = mbb*2 + sub;
    int arow = mb*128 + w*16 + lr;
    if (sub < 1){
      int arown = arow + 128;
      #pragma unroll
      for (int kt = 0; kt < 4; kt++)
        xf[nxt][kt] = ldb8(&xi[((size_t)n*BTOT + arown)*128 + kt*32 + lg*8]);
      #pragma unroll
      for (int kt = 0; kt < 4; kt++)
        xf[nxt][4+kt] = ldb8(&es[((size_t)n*BTOT + arown)*256 + 128 + kt*32 + lg*8]);
    }
    f32x4 a1[8];
    #pragma unroll
    for (int i = 0; i < 8; i++) a1[i] = zero;
    #pragma unroll
    for (int kt = 0; kt < 8; kt++)
      #pragma unroll
      for (int nt = 0; nt < 8; nt++){
        bf16x8 bf = ldb8(&f1T[(nt*16 + lr)*264 + kt*32 + lg*8]);
        a1[nt] = mfma16(xf[cur][kt], bf, a1[nt]);
      }
    #pragma unroll
    for (int nt = 0; nt < 8; nt++){
      int col = nt*16 + lr;
      float bias = f1b[n*128 + col];
      #pragma unroll
      for (int r = 0; r < 4; r++){
        float v = a1[nt][r] + bias;
        v = v > 0.f ? v : 0.01f*v;
        h1T[(w*16 + lg*4 + r)*136 + col] = f2bf(v);
      }
    }
    __syncthreads();
    f32x4 a2[2];
    a2[0] = zero; a2[1] = zero;
    #pragma unroll
    for (int kt = 0; kt < 4; kt++){
      int f0 = kt*32 + lg*8;
      bf16x8 hf = ldb8(&h1T[(w*16 + lr)*136 + f0]);
      #pragma unroll
      for (int nt = 0; nt < 2; nt++){
        bf16x8 bf = ldb8(&f2T[(nt*16 + lr)*136 + f0]);
        a2[nt] = mfma16(hf, bf, a2[nt]);
      }
    }
    #pragma unroll
    for (int nt = 0; nt < 2; nt++){
      int col = nt*16 + lr;
      float bias = f2b[n*32 + col];
      #pragma unroll
      for (int r = 0; r < 4; r++)
        allq[(w*16 + lg*4 + r)*32 + col] = a2[nt][r] + bias;
    }
    __syncthreads();
    if (tid < 128){
      size_t bglob = (size_t)mb*128 + tid;
      int id = ids[(size_t)n*BTOT + bglob];
      out[(size_t)n*BTOT + bglob] = allq[tid*32 + id];
    }
  }
}

extern "C" void kernel_launch(void* const* d_in, const int* in_sizes, int n_in,
                              void* d_out, int out_size, void* d_ws, size_t ws_size,
                              hipStream_t stream){
  if (ws_size < WS_NEED) return;
  const float* obs  = (const float*)d_in[0];
  const float* act  = (const float*)d_in[1];
  const float* gg   = (const float*)d_in[2];
  const float* gb   = (const float*)d_in[3];
  const float* sg   = (const float*)d_in[4];
  const float* sb   = (const float*)d_in[5];
  const float* g_w  = (const float*)d_in[6];
  const float* g_b  = (const float*)d_in[7];
  const float* s_w  = (const float*)d_in[8];
  const float* s_b  = (const float*)d_in[9];
  const float* wq   = (const float*)d_in[10];
  const float* wk   = (const float*)d_in[11];
  const float* wv   = (const float*)d_in[12];
  const float* f1w_in = (const float*)d_in[13];
  const float* f1b  = (const float*)d_in[14];
  const float* f2w_in = (const float*)d_in[15];
  const float* f2b  = (const float*)d_in[16];
  char* ws = (char*)d_ws;
  float* stats   = (float*)(ws + WS_STATS);
  float* scales  = (float*)(ws + WS_SCALES);
  float* bias_es = (float*)(ws + WS_BIASES);
  unsigned short* wqkv = (unsigned short*)(ws + WS_WQKV);
  unsigned short* f2wb = (unsigned short*)(ws + WS_F2W);
  unsigned short* f1wb = (unsigned short*)(ws + WS_F1W);
  unsigned short* wg   = (unsigned short*)(ws + WS_WG);
  int* ids             = (int*)(ws + WS_IDS);
  unsigned short* esb  = (unsigned short*)(ws + WS_ES);
  unsigned short* xib  = (unsigned short*)(ws + WS_XI);
  float* out = (float*)d_out;

  k_zero<<<1, 256, 0, stream>>>(stats);
  k_stats_obs<<<dim3(128,8), 256, 0, stream>>>(obs, stats);
  k_stats_act<<<dim3(256,8), 256, 0, stream>>>(act, stats, ids);
  k_finalize<<<8, 256, 0, stream>>>(stats, gg, gb, sg, sb, scales);
  k_fold<<<3392, 256, 0, stream>>>(g_w, g_b, s_w, s_b, wq, wk, wv, f1w_in, f2w_in,
                                   scales, wg, bias_es, wqkv, f1wb, f2wb);
  k_gemm_es<<<dim3(128,8), 512, 0, stream>>>(obs, act, wg, bias_es, esb);
  k_attn<<<2048, 256, 0, stream>>>(esb, wqkv, xib);
  k_gemm_f<<<dim3(128,8), 512, 0, stream>>>(xib, esb, f1wb, f1b, f2wb, f2b, ids, out);
}